// Round 4
// baseline (41.562 us; speedup 1.0000x reference)
//
#include <hip/hip_runtime.h>
#include <hip/hip_bf16.h>

// out = P*noise + (1-P)*(latent @ W + b), P = prod_{t=1..steps} t/steps
// (closed form of the reference's affine scan)
//
// MFMA formulation: tile = 16 rows; block = 4 waves, wave q owns K-quarter
// q*256..q*256+255 (8x mfma_f32_16x16x32_bf16, acc carried across K — the
// K-loop accumulator recipe). latent/W converted f32->bf16 in-flight
// (error ~1e-2 << 9e-2 threshold). One barrier + 4 LDS reads combine the
// split-K partials; wave q writes D-rows (lane>>4)*4+q.
//
// Fragment layouts (gfx950, learn_hip m89-verified):
//   A: row = lane&15, k = (lane>>4)*8 + j   (8 bf16 / lane)
//   B: col = lane&15, k = (lane>>4)*8 + j
//   D: col = lane&15, row = (lane>>4)*4 + reg

typedef float f32x4  __attribute__((ext_vector_type(4)));
typedef short bf16x8 __attribute__((ext_vector_type(8)));

constexpr int D = 1024;

static __device__ __forceinline__ short f2bf(float f) {
    union { __hip_bfloat16 h; unsigned short u; } cv;
    cv.h = __float2bfloat16(f);
    return (short)cv.u;
}

__global__ __launch_bounds__(256) void diff_init_mfma(
    const float* __restrict__ latent,   // [rows][1024]
    const float* __restrict__ W,        // [1024][3]
    const float* __restrict__ bvec,     // [3]
    const float* __restrict__ noise,    // [rows][3]
    const int*   __restrict__ steps_p,  // scalar
    float*       __restrict__ out,      // [rows][3]
    int rows)
{
    const int lane = threadIdx.x & 63;
    const int q    = threadIdx.x >> 6;      // wave id = K-quarter
    const int row0 = blockIdx.x * 16;

    const int rc = lane & 15;               // A-row (and B-col) index
    const int bq = lane >> 4;               // k-subgroup 0..3

    // ---- B fragments: W slice for this wave's K-quarter, built once ----
    // lane covers col n=rc (zero-padded for n>=3), k = q*256 + i*32 + bq*8 + j
    bf16x8 bfrag[8];
    #pragma unroll
    for (int i = 0; i < 8; ++i) {
        const int kb = q * 256 + i * 32 + bq * 8;
        #pragma unroll
        for (int j = 0; j < 8; ++j) {
            const float v = (rc < 3) ? W[(size_t)(kb + j) * 3 + rc] : 0.0f;
            bfrag[i][j] = f2bf(v);
        }
    }

    // ---- stream latent, 8 MFMAs accumulating over the K-quarter ----
    int arow_i = row0 + rc; if (arow_i > rows - 1) arow_i = rows - 1;
    const float* arow = latent + (size_t)arow_i * D + q * 256 + bq * 8;

    f32x4 acc = {0.f, 0.f, 0.f, 0.f};
    #pragma unroll
    for (int i = 0; i < 8; ++i) {
        const f32x4* p = (const f32x4*)(arow + i * 32);   // 32B/lane, 16 rows x 128B per instr-pair
        const f32x4 a0 = p[0], a1 = p[1];
        bf16x8 af;
        af[0] = f2bf(a0.x); af[1] = f2bf(a0.y);
        af[2] = f2bf(a0.z); af[3] = f2bf(a0.w);
        af[4] = f2bf(a1.x); af[5] = f2bf(a1.y);
        af[6] = f2bf(a1.z); af[7] = f2bf(a1.w);
        acc = __builtin_amdgcn_mfma_f32_16x16x32_bf16(af, bfrag[i], acc, 0, 0, 0);
    }

    // scalar constants (schedules under the MFMA/load drain)
    const int steps = steps_p[0];
    float P = 1.0f;
    for (int t = steps; t >= 1; --t) P *= (float)t / (float)steps;
    const float Q = 1.0f - P;

    // ---- split-K combine via LDS; wave q finishes D-reg q ----
    __shared__ f32x4 part[4][64];
    part[q][lane] = acc;
    __syncthreads();

    const float* pp = (const float*)part;       // [wave][lane][reg] f32
    const float s = pp[(0 * 64 + lane) * 4 + q]
                  + pp[(1 * 64 + lane) * 4 + q]
                  + pp[(2 * 64 + lane) * 4 + q]
                  + pp[(3 * 64 + lane) * 4 + q];

    const int col = rc;                          // D: col = lane&15
    const int row = row0 + bq * 4 + q;           // D: row = (lane>>4)*4 + reg
    if (col < 3 && row < rows) {
        const size_t idx = (size_t)row * 3 + col;
        out[idx] = fmaf(P, noise[idx], Q * (s + bvec[col]));
    }
}

extern "C" void kernel_launch(void* const* d_in, const int* in_sizes, int n_in,
                              void* d_out, int out_size, void* d_ws, size_t ws_size,
                              hipStream_t stream) {
    const float* latent = (const float*)d_in[0];
    const float* W      = (const float*)d_in[1];
    const float* bvec   = (const float*)d_in[2];
    const float* noise  = (const float*)d_in[3];
    const int*   steps  = (const int*)d_in[4];
    float* out = (float*)d_out;

    const int rows   = in_sizes[0] / D;          // 32768
    const int blocks = (rows + 15) / 16;         // 2048 tiles of 16 rows
    diff_init_mfma<<<blocks, 256, 0, stream>>>(latent, W, bvec, noise, steps,
                                               out, rows);
}

// Round 6
// 28.356 us; speedup vs baseline: 1.4657x; 1.4657x over previous
//
#include <hip/hip_runtime.h>

// out = P*noise + (1-P)*(latent @ W + b), P = prod_{t=1..steps} t/steps
// (closed form of the reference's affine scan)
//
// R0 structure (best so far: 1 row/wave grid-stride, per-lane W fragments)
// with the cross-lane reduce moved from DS-unit shuffles (6 x ~120cy serial)
// to VALU DPP adds (6 x ~4cy): row_shr:1/2/4/8 + row_bcast:15/31 puts the
// wave total in lane 63; v_readlane broadcasts it. Zero DS ops in the loop.

typedef float f32x4 __attribute__((ext_vector_type(4)));

constexpr int D = 1024;

// x += dpp_moved(x); ctrl must be a compile-time constant (template param).
// bound_ctrl=true -> out-of-range source lanes contribute 0.
template <int CTRL>
__device__ __forceinline__ float dpp_add(float x) {
    int s = __builtin_amdgcn_update_dpp(0, __float_as_int(x), CTRL, 0xf, 0xf, true);
    return x + __int_as_float(s);
}

// full-wave sum; result valid in lane 63
__device__ __forceinline__ float wave_sum_dpp(float x) {
    x = dpp_add<0x111>(x);  // row_shr:1
    x = dpp_add<0x112>(x);  // row_shr:2
    x = dpp_add<0x114>(x);  // row_shr:4
    x = dpp_add<0x118>(x);  // row_shr:8  -> lanes 15/31/47/63 = 16-lane sums
    x = dpp_add<0x142>(x);  // row_bcast:15 -> lanes 31,63 = 32-lane sums
    x = dpp_add<0x143>(x);  // row_bcast:31 -> lane 63 = full sum
    return x;
}

__global__ __launch_bounds__(256) void diff_init_kernel(
    const float* __restrict__ latent,   // [rows][1024]
    const float* __restrict__ W,        // [1024][3]
    const float* __restrict__ bvec,     // [3]
    const float* __restrict__ noise,    // [rows][3]
    const int*   __restrict__ steps_p,  // scalar
    float*       __restrict__ out,      // [rows][3]
    int rows)
{
    const int lane   = threadIdx.x & 63;
    const int wave   = blockIdx.x * (blockDim.x >> 6) + (threadIdx.x >> 6);
    const int nwaves = gridDim.x * (blockDim.x >> 6);

    const int steps = steps_p[0];
    float P = 1.0f;
    for (int t = steps; t >= 1; --t) P *= (float)t / (float)steps;
    const float Q = 1.0f - P;

    // Per-lane W fragment: float4-chunk idx = it*64+lane covers d in
    // [idx*4, idx*4+4); 4 d's x 3 cols = 12 consecutive floats at idx*48 B.
    float w[4][12];
    #pragma unroll
    for (int it = 0; it < 4; ++it) {
        const f32x4* wp = (const f32x4*)(W + (size_t)(it * 64 + lane) * 12);
        f32x4 wa = wp[0], wb = wp[1], wc = wp[2];
        w[it][0] = wa.x; w[it][1]  = wa.y; w[it][2]  = wa.z; w[it][3]  = wa.w;
        w[it][4] = wb.x; w[it][5]  = wb.y; w[it][6]  = wb.z; w[it][7]  = wb.w;
        w[it][8] = wc.x; w[it][9]  = wc.y; w[it][10] = wc.z; w[it][11] = wc.w;
    }

    const float bb = (lane < 3) ? bvec[lane] : 0.0f;

    for (int row = wave; row < rows; row += nwaves) {
        const f32x4* lrow = (const f32x4*)(latent + (size_t)row * D);
        // issue noise load early so its latency hides under the FMAs
        const float nz = (lane < 3) ? noise[(size_t)row * 3 + lane] : 0.0f;

        float a0 = 0.f, a1 = 0.f, a2 = 0.f;
        #pragma unroll
        for (int it = 0; it < 4; ++it) {
            f32x4 lv = lrow[it * 64 + lane];          // coalesced 1 KiB/instr
            a0 = fmaf(lv.x, w[it][0], a0);
            a1 = fmaf(lv.x, w[it][1], a1);
            a2 = fmaf(lv.x, w[it][2], a2);
            a0 = fmaf(lv.y, w[it][3], a0);
            a1 = fmaf(lv.y, w[it][4], a1);
            a2 = fmaf(lv.y, w[it][5], a2);
            a0 = fmaf(lv.z, w[it][6], a0);
            a1 = fmaf(lv.z, w[it][7], a1);
            a2 = fmaf(lv.z, w[it][8], a2);
            a0 = fmaf(lv.w, w[it][9],  a0);
            a1 = fmaf(lv.w, w[it][10], a1);
            a2 = fmaf(lv.w, w[it][11], a2);
        }

        // VALU-only reduce: 3 independent DPP chains, totals in lane 63
        const float sa = wave_sum_dpp(a0);
        const float sb = wave_sum_dpp(a1);
        const float sc = wave_sum_dpp(a2);
        const float ra = __int_as_float(__builtin_amdgcn_readlane(__float_as_int(sa), 63));
        const float rb = __int_as_float(__builtin_amdgcn_readlane(__float_as_int(sb), 63));
        const float rc = __int_as_float(__builtin_amdgcn_readlane(__float_as_int(sc), 63));

        if (lane < 3) {
            const float t = (lane == 0) ? ra : (lane == 1) ? rb : rc;
            out[(size_t)row * 3 + lane] = fmaf(P, nz, Q * (t + bb));
        }
    }
}

extern "C" void kernel_launch(void* const* d_in, const int* in_sizes, int n_in,
                              void* d_out, int out_size, void* d_ws, size_t ws_size,
                              hipStream_t stream) {
    const float* latent = (const float*)d_in[0];
    const float* W      = (const float*)d_in[1];
    const float* bvec   = (const float*)d_in[2];
    const float* noise  = (const float*)d_in[3];
    const int*   steps  = (const int*)d_in[4];
    float* out = (float*)d_out;

    const int rows = in_sizes[0] / D;           // 4*8192 = 32768
    const int blocks = 2048;                    // 8 blocks/CU, grid-stride rows
    diff_init_kernel<<<blocks, 256, 0, stream>>>(latent, W, bvec, noise, steps,
                                                 out, rows);
}